// Round 1
// baseline (137.827 us; speedup 1.0000x reference)
//
#include <hip/hip_runtime.h>

#define N_BATCH   50000
#define N_FEATURE 128
#define DEPTH     9
#define N_TREE    200
#define N_NODE    1023
#define N_OUTPUT  8

#define BPB     64                            // batches per block (lanes)
#define WAVES   8
#define BLOCK   (WAVES * 64)                  // 512 threads
#define TPR     8                             // trees per round (1 per wave)
#define ROUNDS  (N_TREE / TPR)                // 25

// Grid: 768 monolithic chunk-blocks (3/CU x 256 CU, one clean phase) + 14
// surplus chunks shattered into 25 single-round blocks that backfill.
#define FULL_CHUNKS 768
#define NCHUNK      ((N_BATCH + BPB - 1) / BPB)     // 782
#define TAIL_CHUNKS (NCHUNK - FULL_CHUNKS)          // 14
#define TAIL_SPLIT  ROUNDS
#define TAIL_BLOCKS (TAIL_CHUNKS * TAIL_SPLIT)      // 350
#define GRID        (FULL_CHUNKS + TAIL_BLOCKS)     // 1118

// Per-wave private buffer, 1 tree: shifted heap copy
//   thS[k] = th[k+1] (k=0..511)   [2048 B]   pair(n) = float2 @ thS[2n] (8B aligned)
//   fS[k]  = feat[k+1] u8         [512 B]    fpair(n) = u16 @ fS[2n]
// Root record is NOT staged: it is wave-uniform -> kept in SGPRs (s_load).
// Staging is quad-vectorized: lane q writes nodes 4q+1..4q+4 with one
// ds_write_b128 (th) + one ds_write_b32 (4 packed feat bytes).
#define TREE_B  2560
#define REC_B   (WAVES * TREE_B)              // 20480

__global__ __launch_bounds__(BLOCK, 6)        // 6 waves/EU -> 3 blocks/CU, 24 waves/CU
void tree_kernel(const float* __restrict__ x,
                 const int*   __restrict__ feature,
                 const float* __restrict__ threshold,
                 const float* __restrict__ value,
                 float*       __restrict__ out)
{
    __shared__ float xt[N_FEATURE * BPB];           // 32 KB, xt[f*64+b]: bank = lane%32 (free)
    __shared__ __align__(16) char recbuf[REC_B];    // 20 KB, 8 wave-private 2560B slices

    const int tid = threadIdx.x;
    const int bid = blockIdx.x;
    const int b   = tid & 63;                       // lane = batch within chunk
    const int g   = tid >> 6;                       // wave id: tree g of each round
    char* wbuf = recbuf + g * TREE_B;

    int chunk, r0, r1; bool tail;
    if (bid < FULL_CHUNKS) { chunk = bid; r0 = 0; r1 = ROUNDS; tail = false; }
    else {
        const int t2 = bid - FULL_CHUNKS;
        chunk = FULL_CHUNKS + t2 / TAIL_SPLIT;
        r0 = t2 % TAIL_SPLIT; r1 = r0 + 1; tail = true;
    }

    // uniform tree-row bases: readfirstlane(g) -> scalar address -> s_load roots
    const int g_u = __builtin_amdgcn_readfirstlane(g);
    const float* trow  = threshold + (size_t)(r0 * TPR + g_u) * N_NODE;
    const int*   frow  = feature   + (size_t)(r0 * TPR + g_u) * N_NODE;
    const float* vbase = value + (size_t)(r0 * TPR + g_u) * (N_NODE * N_OUTPUT);

    // per-lane packed-quad sources: nodes 4q+1..4q+4, q = b and q = b+64
    // (dword-aligned dwordx4; HW supports 4B-aligned x4 loads, L2-hot)
    const float* tq = trow + 1 + 4 * b;
    const int*   fq = frow + 1 + 4 * b;

    // ---- prefetch round-r0 records (4 x dwordx4 + 2 scalar roots) ----
    float4 tA, tB; int4 fA, fB;
    __builtin_memcpy(&tA, tq, 16);
    __builtin_memcpy(&tB, tq + 256, 16);
    __builtin_memcpy(&fA, fq, 16);
    __builtin_memcpy(&fB, fq + 256, 16);
    float th0 = trow[0];                            // uniform -> s_load_dword
    int   f0  = frow[0];

    // ---- stage x chunk transposed into LDS (conflict-free via XOR-swizzled R) ----
    {
        const float4* x4 = (const float4*)x;
        float4* R = (float4*)recbuf;                // 16 KB alias (pre-round only)
        #pragma unroll
        for (int rr = 0; rr < 2; ++rr) {
            #pragma unroll
            for (int k = 0; k < 2; ++k) {           // 1024 float4 / 512 thr = 2 iters
                const int j  = tid + k * BLOCK;
                const int bl = j >> 5, f4 = j & 31;
                const int gb = chunk * BPB + rr * 32 + bl;
                float4 v = (gb < N_BATCH) ? x4[(size_t)gb * 32 + f4]
                                          : make_float4(0.f, 0.f, 0.f, 0.f);
                R[bl * 32 + (f4 ^ bl)] = v;
            }
            __syncthreads();
            {
                const int b32 = tid & 31, fc = tid >> 5;   // fc = 0..15
                const int bb = rr * 32 + b32;
                #pragma unroll
                for (int c = 0; c < 2; ++c) {
                    const int f4 = fc * 2 + c;
                    float4 v = R[b32 * 32 + (f4 ^ b32)];
                    xt[(f4 * 4 + 0) * BPB + bb] = v.x;
                    xt[(f4 * 4 + 1) * BPB + bb] = v.y;
                    xt[(f4 * 4 + 2) * BPB + bb] = v.z;
                    xt[(f4 * 4 + 3) * BPB + bb] = v.w;
                }
            }
            __syncthreads();
        }
    }
    // No block barriers from here until the final reduction: each wave owns
    // wbuf exclusively, ordered by its own lgkmcnt waits.

    float acc[N_OUTPUT];
    #pragma unroll
    for (int o = 0; o < N_OUTPUT; ++o) acc[o] = 0.f;
    float4 vp0 = make_float4(0.f, 0.f, 0.f, 0.f);   // leaf-value pipeline regs
    float4 vp1 = make_float4(0.f, 0.f, 0.f, 0.f);

    float*         thS = (float*)wbuf;
    unsigned char* fS  = (unsigned char*)(wbuf + 2048);

    for (int r = r0; r < r1; ++r) {
        __asm__ volatile("s_waitcnt lgkmcnt(0)" ::: "memory");   // WAR on wbuf
        // quad-vector staging: 2 x ds_write_b128 + 2 x ds_write_b32
        ((float4*)thS)[b]      = tA;
        ((float4*)thS)[b + 64] = tB;
        {
            const unsigned pA = (fA.x & 255) | ((fA.y & 255) << 8) |
                                ((fA.z & 255) << 16) | ((unsigned)fA.w << 24);
            const unsigned pB = (fB.x & 255) | ((fB.y & 255) << 8) |
                                ((fB.z & 255) << 16) | ((unsigned)fB.w << 24);
            ((unsigned*)fS)[b]      = pA;
            ((unsigned*)fS)[b + 64] = pB;
        }
        __asm__ volatile("s_waitcnt lgkmcnt(0)" ::: "memory");   // RAW visibility

        const float th0c = th0; const int f0c = f0;              // this round's root
        if (r + 1 < r1) {                           // prefetch next round (regs now free)
            trow += TPR * N_NODE; frow += TPR * N_NODE;
            tq   += TPR * N_NODE; fq   += TPR * N_NODE;
            __builtin_memcpy(&tA, tq, 16);
            __builtin_memcpy(&tB, tq + 256, 16);
            __builtin_memcpy(&fA, fq, 16);
            __builtin_memcpy(&fB, fq + 256, 16);
            th0 = trow[0]; f0 = frow[0];
        }

        // ---- traverse 1 tree; root record in SGPRs, next pair from LDS ----
        int   m  = 1;                               // 1-indexed node: child = 2m+s
        float th = th0c;
        int   fv = f0c;
        float2 c = ((float2*)thS)[0];               // children of root
        int   k2 = ((unsigned short*)fS)[0];
        int   fl = k2 & 255, fh = k2 >> 8;
        #pragma unroll
        for (int d = 0; d < DEPTH; ++d) {
            const float xv = xt[fv * BPB + b];      // only on-chain LDS read
            const int s = (xv > th) ? 1 : 0;        // xval <= split -> left
            m = 2 * m + s;
            if (d < DEPTH - 1) {
                th = s ? c.y : c.x;
                fv = s ? fh : fl;
            }
            if (d < DEPTH - 2) {                    // speculative pair read (m-1 <= 254)
                c  = ((float2*)thS)[m - 1];
                k2 = ((unsigned short*)fS)[m - 1];
                fl = k2 & 255; fh = k2 >> 8;
            }
        }
        // ---- software-pipelined leaf gather: load now, accumulate next round ----
        {
            const float4* vp = (const float4*)(vbase + (size_t)(m - 1) * N_OUTPUT);
            const float4 n0 = vp[0], n1 = vp[1];
            acc[0] += vp0.x; acc[1] += vp0.y; acc[2] += vp0.z; acc[3] += vp0.w;
            acc[4] += vp1.x; acc[5] += vp1.y; acc[6] += vp1.z; acc[7] += vp1.w;
            vp0 = n0; vp1 = n1;
        }
        vbase += (size_t)TPR * (N_NODE * N_OUTPUT);
    }
    // drain value pipeline (preserves per-round add order -> bit-identical)
    acc[0] += vp0.x; acc[1] += vp0.y; acc[2] += vp0.z; acc[3] += vp0.w;
    acc[4] += vp1.x; acc[5] += vp1.y; acc[6] += vp1.z; acc[7] += vp1.w;

    // ---- reduce 8 waves' partials (alias recbuf, stride-9 pad) ----
    __syncthreads();
    float* red = (float*)recbuf;                    // 8*576*4 = 18432 <= 20480
    {
        float* dst = red + (g * 576 + b * 9);
        #pragma unroll
        for (int o = 0; o < N_OUTPUT; ++o) dst[o] = acc[o];
    }
    __syncthreads();
    {
        const int bl = tid >> 3, o = tid & 7;       // 512 threads = 64 batches x 8 outs
        const int bg = chunk * BPB + bl;
        float s = 0.f;
        #pragma unroll
        for (int gg = 0; gg < WAVES; ++gg) s += red[gg * 576 + bl * 9 + o];
        s *= (1.0f / N_TREE);
        if (!tail) {
            out[(size_t)chunk * (BPB * N_OUTPUT) + tid] = s;   // coalesced, exactly once
        } else if (bg < N_BATCH) {
            atomicAdd(out + (size_t)bg * N_OUTPUT + o, s);
        }
    }
}

extern "C" void kernel_launch(void* const* d_in, const int* in_sizes, int n_in,
                              void* d_out, int out_size, void* d_ws, size_t ws_size,
                              hipStream_t stream) {
    const float* x         = (const float*)d_in[0];
    const int*   feature   = (const int*)d_in[1];
    const float* threshold = (const float*)d_in[2];
    const float* value     = (const float*)d_in[5];   // children implied by complete heap layout
    float* out = (float*)d_out;

    // zero only the tail-chunk region (atomic accumulation); ~27 KB
    const size_t tail_off = (size_t)FULL_CHUNKS * BPB * N_OUTPUT;
    if ((size_t)out_size > tail_off) {
        hipMemsetAsync(out + tail_off, 0, ((size_t)out_size - tail_off) * sizeof(float), stream);
    }

    tree_kernel<<<dim3(GRID), dim3(BLOCK), 0, stream>>>(x, feature, threshold, value, out);
}

// Round 2
// 135.219 us; speedup vs baseline: 1.0193x; 1.0193x over previous
//
#include <hip/hip_runtime.h>

#define N_BATCH   50000
#define N_FEATURE 128
#define DEPTH     9
#define N_TREE    200
#define N_NODE    1023
#define N_OUTPUT  8

#define BPB     64                            // batches per block (lanes)
#define WAVES   8
#define BLOCK   (WAVES * 64)                  // 512 threads
#define TPR     8                             // trees per round (1 per wave)
#define ROUNDS  (N_TREE / TPR)                // 25

// Grid: 768 monolithic chunk-blocks (3/CU x 256 CU, one clean phase) + 14
// surplus chunks shattered into 25 single-round blocks that backfill.
#define FULL_CHUNKS 768
#define NCHUNK      ((N_BATCH + BPB - 1) / BPB)     // 782
#define TAIL_CHUNKS (NCHUNK - FULL_CHUNKS)          // 14
#define TAIL_SPLIT  ROUNDS
#define TAIL_BLOCKS (TAIL_CHUNKS * TAIL_SPLIT)      // 350
#define GRID        (FULL_CHUNKS + TAIL_BLOCKS)     // 1118

// Per-wave private buffer, 1 tree: shifted heap copy
//   thS[k] = th[k+1] (k=0..510)   [2048 B]   pair(n) = float2 @ thS[2n] (8B aligned)
//   fS[k]  = feat[k+1] u8         [512 B]    fpair(n) = u16 @ fS[2n]
// Root th/feat + root children come from v_readlane of the prefetch regs
// (lane b holds node b), so the root is never read back from LDS.
// NO explicit lgkmcnt barriers in the round loop: DS ops of a wave execute
// in program order (WAR/RAW safe); compiler inserts data-arrival waits.
#define TREE_B  2560
#define REC_B   (WAVES * TREE_B)              // 20480

__device__ __forceinline__ float readlane_f(float v, int lane) {
    return __int_as_float(__builtin_amdgcn_readlane(__float_as_int(v), lane));
}

__global__ __launch_bounds__(BLOCK, 6)        // 6 waves/EU -> 3 blocks/CU, 24 waves/CU
void tree_kernel(const float* __restrict__ x,
                 const int*   __restrict__ feature,
                 const float* __restrict__ threshold,
                 const float* __restrict__ value,
                 float*       __restrict__ out)
{
    __shared__ float xt[N_FEATURE * BPB];           // 32 KB, xt[f*64+b]: bank = lane%32 (free)
    __shared__ __align__(16) char recbuf[REC_B];    // 20 KB, 8 wave-private 2560B slices

    const int tid = threadIdx.x;
    const int bid = blockIdx.x;
    const int b   = tid & 63;                       // lane = batch within chunk
    const int g   = tid >> 6;                       // wave id: tree g of each round
    char* wbuf = recbuf + g * TREE_B;

    int chunk, r0, r1; bool tail;
    if (bid < FULL_CHUNKS) { chunk = bid; r0 = 0; r1 = ROUNDS; tail = false; }
    else {
        const int t2 = bid - FULL_CHUNKS;
        chunk = FULL_CHUNKS + t2 / TAIL_SPLIT;
        r0 = t2 % TAIL_SPLIT; r1 = r0 + 1; tail = true;
    }

    // incremental per-round bases (avoid 64-bit muls in the loop)
    const float* tpre = threshold + (size_t)(r0 * TPR + g) * N_NODE + b;
    const int*   fpre = feature   + (size_t)(r0 * TPR + g) * N_NODE + b;
    const float* vbase = value + (size_t)(r0 * TPR + g) * N_NODE * N_OUTPUT;

    // ---- prefetch round-r0 records (dense coalesced, imm-offset friendly) ----
    float thr[8]; int fr[8];
    #pragma unroll
    for (int j = 0; j < 8; ++j) { thr[j] = tpre[j * 64]; fr[j] = fpre[j * 64]; }

    // ---- stage x chunk transposed into LDS (conflict-free via XOR-swizzled R) ----
    {
        const float4* x4 = (const float4*)x;
        float4* R = (float4*)recbuf;                // 16 KB alias (pre-round only)
        #pragma unroll
        for (int rr = 0; rr < 2; ++rr) {
            #pragma unroll
            for (int k = 0; k < 2; ++k) {           // 1024 float4 / 512 thr = 2 iters
                const int j  = tid + k * BLOCK;
                const int bl = j >> 5, f4 = j & 31;
                const int gb = chunk * BPB + rr * 32 + bl;
                float4 v = (gb < N_BATCH) ? x4[(size_t)gb * 32 + f4]
                                          : make_float4(0.f, 0.f, 0.f, 0.f);
                R[bl * 32 + (f4 ^ bl)] = v;
            }
            __syncthreads();
            {
                const int b32 = tid & 31, fc = tid >> 5;   // fc = 0..15
                const int bb = rr * 32 + b32;
                #pragma unroll
                for (int c = 0; c < 2; ++c) {
                    const int f4 = fc * 2 + c;
                    float4 v = R[b32 * 32 + (f4 ^ b32)];
                    xt[(f4 * 4 + 0) * BPB + bb] = v.x;
                    xt[(f4 * 4 + 1) * BPB + bb] = v.y;
                    xt[(f4 * 4 + 2) * BPB + bb] = v.z;
                    xt[(f4 * 4 + 3) * BPB + bb] = v.w;
                }
            }
            __syncthreads();
        }
    }
    // No block barriers from here until the final reduction: each wave owns
    // wbuf exclusively; per-wave DS program order provides WAR/RAW safety.

    float acc[N_OUTPUT];
    #pragma unroll
    for (int o = 0; o < N_OUTPUT; ++o) acc[o] = 0.f;
    float4 vp0 = make_float4(0.f, 0.f, 0.f, 0.f);   // leaf-value pipeline regs
    float4 vp1 = make_float4(0.f, 0.f, 0.f, 0.f);

    float*         thS = (float*)wbuf;
    unsigned char* fS  = (unsigned char*)(wbuf + 2048);

    for (int r = r0; r < r1; ++r) {
        // ---- stage this round's tree (16 scalar DS writes, proven pattern) ----
        #pragma unroll
        for (int j = 0; j < 8; ++j) {               // shifted copy, branchless dst
            const int dst = (b + j * 64 - 1) & 511; // node 0 -> 511 (unused root slot)
            thS[dst] = thr[j];
            fS[dst]  = (unsigned char)fr[j];
        }

        // ---- root + root-children from registers (readlane; no DS, no SMEM) ----
        // lane b's thr[0]/fr[0] holds node b: lanes 0,1,2 = root, left, right.
        const float th0 = readlane_f(thr[0], 0);
        const int   f0  = __builtin_amdgcn_readlane(fr[0], 0);
        const float cx0 = readlane_f(thr[0], 1);
        const float cy0 = readlane_f(thr[0], 2);
        const int   fl0 = __builtin_amdgcn_readlane(fr[0], 1);
        const int   fh0 = __builtin_amdgcn_readlane(fr[0], 2);

        if (r + 1 < r1) {                           // dense coalesced prefetch, next round
            const float* tn = tpre + TPR * N_NODE;
            const int*   fn = fpre + TPR * N_NODE;
            #pragma unroll
            for (int j = 0; j < 8; ++j) { thr[j] = tn[j * 64]; fr[j] = fn[j * 64]; }
            tpre = tn; fpre = fn;
        }

        // ---- traverse 1 tree; 1-indexed node m, children th via pair reads ----
        int   m  = 1;
        float th = th0;
        int   fv = f0;
        float2 c = make_float2(cx0, cy0);           // children of root (regs)
        int   fl = fl0, fh = fh0;
        #pragma unroll
        for (int d = 0; d < DEPTH; ++d) {
            const float xv = xt[fv * BPB + b];      // only on-chain LDS read
            const int s = (xv > th) ? 1 : 0;        // xval <= split -> left
            m = 2 * m + s;
            if (d < DEPTH - 1) {
                th = s ? c.y : c.x;
                fv = s ? fh : fl;
            }
            if (d < DEPTH - 2) {                    // speculative pair read (m-1 <= 254)
                c = ((float2*)thS)[m - 1];
                const int k2 = ((unsigned short*)fS)[m - 1];
                fl = k2 & 255; fh = k2 >> 8;        // off-chain extraction
            }
        }
        // ---- software-pipelined leaf gather: load now, accumulate next round ----
        {
            const float4* vp = (const float4*)(vbase + (size_t)(m - 1) * N_OUTPUT);
            const float4 n0 = vp[0], n1 = vp[1];
            acc[0] += vp0.x; acc[1] += vp0.y; acc[2] += vp0.z; acc[3] += vp0.w;
            acc[4] += vp1.x; acc[5] += vp1.y; acc[6] += vp1.z; acc[7] += vp1.w;
            vp0 = n0; vp1 = n1;
        }
        vbase += (size_t)TPR * N_NODE * N_OUTPUT;
    }
    // drain value pipeline (preserves per-round add order -> bit-identical)
    acc[0] += vp0.x; acc[1] += vp0.y; acc[2] += vp0.z; acc[3] += vp0.w;
    acc[4] += vp1.x; acc[5] += vp1.y; acc[6] += vp1.z; acc[7] += vp1.w;

    // ---- reduce 8 waves' partials (alias recbuf, stride-9 pad) ----
    __syncthreads();
    float* red = (float*)recbuf;                    // 8*576*4 = 18432 <= 20480
    {
        float* dst = red + (g * 576 + b * 9);
        #pragma unroll
        for (int o = 0; o < N_OUTPUT; ++o) dst[o] = acc[o];
    }
    __syncthreads();
    {
        const int bl = tid >> 3, o = tid & 7;       // 512 threads = 64 batches x 8 outs
        const int bg = chunk * BPB + bl;
        float s = 0.f;
        #pragma unroll
        for (int gg = 0; gg < WAVES; ++gg) s += red[gg * 576 + bl * 9 + o];
        s *= (1.0f / N_TREE);
        if (!tail) {
            out[(size_t)chunk * (BPB * N_OUTPUT) + tid] = s;   // coalesced, exactly once
        } else if (bg < N_BATCH) {
            atomicAdd(out + (size_t)bg * N_OUTPUT + o, s);
        }
    }
}

extern "C" void kernel_launch(void* const* d_in, const int* in_sizes, int n_in,
                              void* d_out, int out_size, void* d_ws, size_t ws_size,
                              hipStream_t stream) {
    const float* x         = (const float*)d_in[0];
    const int*   feature   = (const int*)d_in[1];
    const float* threshold = (const float*)d_in[2];
    const float* value     = (const float*)d_in[5];   // children implied by complete heap layout
    float* out = (float*)d_out;

    // zero only the tail-chunk region (atomic accumulation); ~27 KB
    const size_t tail_off = (size_t)FULL_CHUNKS * BPB * N_OUTPUT;
    if ((size_t)out_size > tail_off) {
        hipMemsetAsync(out + tail_off, 0, ((size_t)out_size - tail_off) * sizeof(float), stream);
    }

    tree_kernel<<<dim3(GRID), dim3(BLOCK), 0, stream>>>(x, feature, threshold, value, out);
}

// Round 3
// 134.681 us; speedup vs baseline: 1.0234x; 1.0040x over previous
//
#include <hip/hip_runtime.h>

#define N_BATCH   50000
#define N_FEATURE 128
#define DEPTH     9
#define N_TREE    200
#define N_NODE    1023
#define N_OUTPUT  8

#define BPB     64                            // batches per block (lanes)
#define WAVES   8
#define BLOCK   (WAVES * 64)                  // 512 threads
#define TPR     8                             // trees per round (1 per wave)
#define ROUNDS  (N_TREE / TPR)                // 25

// Grid: 768 monolithic chunk-blocks (3/CU x 256 CU, one clean phase) + 14
// surplus chunks shattered into 25 single-round blocks that backfill.
#define FULL_CHUNKS 768
#define NCHUNK      ((N_BATCH + BPB - 1) / BPB)     // 782
#define TAIL_CHUNKS (NCHUNK - FULL_CHUNKS)          // 14
#define TAIL_SPLIT  ROUNDS
#define TAIL_BLOCKS (TAIL_CHUNKS * TAIL_SPLIT)      // 350
#define GRID        (FULL_CHUNKS + TAIL_BLOCKS)     // 1118

// Per-wave private buffer, 1 tree: shifted heap copy
//   thS[k] = th[k+1] (k=0..511)   [2048 B]   pair(n) = float2 @ thS[2n] (8B aligned)
//   fS[k]  = feat[k+1] u8         [512 B]    fpair(n) = u16 @ fS[2n]
// Staging is quad-vectorized: lane q holds nodes 4q+1..4q+4 in regs, writes
// them with ds_write_b128 (th) + ds_write_b32 (4 packed feat bytes).
// Root th/feat come from an all-lanes-uniform VECTOR load (vmcnt, never SMEM
// -> lgkm waits for DS stay precise); root children via readlane(lane 0).
// NO explicit lgkmcnt barriers in the round loop: DS ops of a wave execute
// in program order (WAR/RAW safe); compiler inserts data-arrival waits.
#define TREE_B  2560
#define REC_B   (WAVES * TREE_B)              // 20480

__device__ __forceinline__ float readlane_f(float v, int lane) {
    return __int_as_float(__builtin_amdgcn_readlane(__float_as_int(v), lane));
}

__global__ __launch_bounds__(BLOCK, 6)        // 6 waves/EU -> 3 blocks/CU, 24 waves/CU
void tree_kernel(const float* __restrict__ x,
                 const int*   __restrict__ feature,
                 const float* __restrict__ threshold,
                 const float* __restrict__ value,
                 float*       __restrict__ out)
{
    __shared__ float xt[N_FEATURE * BPB];           // 32 KB, xt[f*64+b]: bank = lane%32 (free)
    __shared__ __align__(16) char recbuf[REC_B];    // 20 KB, 8 wave-private 2560B slices

    const int tid = threadIdx.x;
    const int bid = blockIdx.x;
    const int b   = tid & 63;                       // lane = batch within chunk
    const int g   = tid >> 6;                       // wave id: tree g of each round
    char* wbuf = recbuf + g * TREE_B;

    int chunk, r0, r1; bool tail;
    if (bid < FULL_CHUNKS) { chunk = bid; r0 = 0; r1 = ROUNDS; tail = false; }
    else {
        const int t2 = bid - FULL_CHUNKS;
        chunk = FULL_CHUNKS + t2 / TAIL_SPLIT;
        r0 = t2 % TAIL_SPLIT; r1 = r0 + 1; tail = true;
    }

    // per-round tree-row bases (g is uniform per wave but kept in VGPR form so
    // the root loads stay VECTOR loads -> vmcnt, not SMEM/lgkm)
    const float* trow  = threshold + (size_t)(r0 * TPR + g) * N_NODE;
    const int*   frow  = feature   + (size_t)(r0 * TPR + g) * N_NODE;
    const float* vbase = value + (size_t)(r0 * TPR + g) * N_NODE * N_OUTPUT;

    // per-lane packed-quad sources: nodes 4q+1..4q+4, q = b and q = b+64
    const float* tq = trow + 1 + 4 * b;
    const int*   fq = frow + 1 + 4 * b;

    // ---- prefetch round-r0 records (4 x dwordx4 + broadcast root) ----
    float4 tA, tB; int4 fA, fB;
    __builtin_memcpy(&tA, tq, 16);
    __builtin_memcpy(&tB, tq + 256, 16);
    __builtin_memcpy(&fA, fq, 16);
    __builtin_memcpy(&fB, fq + 256, 16);
    float th0 = trow[0];                            // uniform addr vector load
    int   f0  = frow[0];

    // ---- stage x chunk transposed into LDS (conflict-free via XOR-swizzled R) ----
    {
        const float4* x4 = (const float4*)x;
        float4* R = (float4*)recbuf;                // 16 KB alias (pre-round only)
        #pragma unroll
        for (int rr = 0; rr < 2; ++rr) {
            #pragma unroll
            for (int k = 0; k < 2; ++k) {           // 1024 float4 / 512 thr = 2 iters
                const int j  = tid + k * BLOCK;
                const int bl = j >> 5, f4 = j & 31;
                const int gb = chunk * BPB + rr * 32 + bl;
                float4 v = (gb < N_BATCH) ? x4[(size_t)gb * 32 + f4]
                                          : make_float4(0.f, 0.f, 0.f, 0.f);
                R[bl * 32 + (f4 ^ bl)] = v;
            }
            __syncthreads();
            {
                const int b32 = tid & 31, fc = tid >> 5;   // fc = 0..15
                const int bb = rr * 32 + b32;
                #pragma unroll
                for (int c = 0; c < 2; ++c) {
                    const int f4 = fc * 2 + c;
                    float4 v = R[b32 * 32 + (f4 ^ b32)];
                    xt[(f4 * 4 + 0) * BPB + bb] = v.x;
                    xt[(f4 * 4 + 1) * BPB + bb] = v.y;
                    xt[(f4 * 4 + 2) * BPB + bb] = v.z;
                    xt[(f4 * 4 + 3) * BPB + bb] = v.w;
                }
            }
            __syncthreads();
        }
    }
    // No block barriers from here until the final reduction: each wave owns
    // wbuf exclusively; per-wave DS program order provides WAR/RAW safety.

    float acc[N_OUTPUT];
    #pragma unroll
    for (int o = 0; o < N_OUTPUT; ++o) acc[o] = 0.f;
    float4 vp0 = make_float4(0.f, 0.f, 0.f, 0.f);   // leaf-value pipeline regs
    float4 vp1 = make_float4(0.f, 0.f, 0.f, 0.f);

    float*         thS = (float*)wbuf;
    unsigned char* fS  = (unsigned char*)(wbuf + 2048);

    for (int r = r0; r < r1; ++r) {
        // ---- quad-vector staging: 2 x ds_write_b128 + 2 x ds_write_b32 ----
        ((float4*)thS)[b]      = tA;                // nodes 4b+1..4b+4 -> thS[4b..]
        ((float4*)thS)[b + 64] = tB;                // nodes 4b+257..260
        {
            const unsigned pA = (fA.x & 255) | ((fA.y & 255) << 8) |
                                ((fA.z & 255) << 16) | ((unsigned)fA.w << 24);
            const unsigned pB = (fB.x & 255) | ((fB.y & 255) << 8) |
                                ((fB.z & 255) << 16) | ((unsigned)fB.w << 24);
            ((unsigned*)fS)[b]      = pA;
            ((unsigned*)fS)[b + 64] = pB;
        }

        // ---- root (broadcast regs) + root children (readlane of lane 0's quad) ----
        const float th0c = th0; const int f0c = f0;
        const float cx0 = readlane_f(tA.x, 0);      // node 1 threshold
        const float cy0 = readlane_f(tA.y, 0);      // node 2 threshold
        const int   fl0 = __builtin_amdgcn_readlane(fA.x, 0);
        const int   fh0 = __builtin_amdgcn_readlane(fA.y, 0);

        if (r + 1 < r1) {                           // prefetch next round (regs now free)
            trow += TPR * N_NODE; frow += TPR * N_NODE;
            tq   += TPR * N_NODE; fq   += TPR * N_NODE;
            __builtin_memcpy(&tA, tq, 16);
            __builtin_memcpy(&tB, tq + 256, 16);
            __builtin_memcpy(&fA, fq, 16);
            __builtin_memcpy(&fB, fq + 256, 16);
            th0 = trow[0]; f0 = frow[0];
        }

        // ---- traverse 1 tree; 1-indexed node m, children th via pair reads ----
        int   m  = 1;
        float th = th0c;
        int   fv = f0c;
        float2 c = make_float2(cx0, cy0);           // children of root (regs)
        int   fl = fl0, fh = fh0;
        #pragma unroll
        for (int d = 0; d < DEPTH; ++d) {
            const float xv = xt[fv * BPB + b];      // only on-chain LDS read
            const int s = (xv > th) ? 1 : 0;        // xval <= split -> left
            m = 2 * m + s;
            if (d < DEPTH - 1) {
                th = s ? c.y : c.x;
                fv = s ? fh : fl;
            }
            if (d < DEPTH - 2) {                    // speculative pair read (m-1 <= 254)
                c = ((float2*)thS)[m - 1];
                const int k2 = ((unsigned short*)fS)[m - 1];
                fl = k2 & 255; fh = k2 >> 8;        // off-chain extraction
            }
        }
        // ---- software-pipelined leaf gather: load now, accumulate next round ----
        {
            const float4* vp = (const float4*)(vbase + (size_t)(m - 1) * N_OUTPUT);
            const float4 n0 = vp[0], n1 = vp[1];
            acc[0] += vp0.x; acc[1] += vp0.y; acc[2] += vp0.z; acc[3] += vp0.w;
            acc[4] += vp1.x; acc[5] += vp1.y; acc[6] += vp1.z; acc[7] += vp1.w;
            vp0 = n0; vp1 = n1;
        }
        vbase += (size_t)TPR * N_NODE * N_OUTPUT;
    }
    // drain value pipeline (preserves per-round add order -> bit-identical)
    acc[0] += vp0.x; acc[1] += vp0.y; acc[2] += vp0.z; acc[3] += vp0.w;
    acc[4] += vp1.x; acc[5] += vp1.y; acc[6] += vp1.z; acc[7] += vp1.w;

    // ---- reduce 8 waves' partials (alias recbuf, stride-9 pad) ----
    __syncthreads();
    float* red = (float*)recbuf;                    // 8*576*4 = 18432 <= 20480
    {
        float* dst = red + (g * 576 + b * 9);
        #pragma unroll
        for (int o = 0; o < N_OUTPUT; ++o) dst[o] = acc[o];
    }
    __syncthreads();
    {
        const int bl = tid >> 3, o = tid & 7;       // 512 threads = 64 batches x 8 outs
        const int bg = chunk * BPB + bl;
        float s = 0.f;
        #pragma unroll
        for (int gg = 0; gg < WAVES; ++gg) s += red[gg * 576 + bl * 9 + o];
        s *= (1.0f / N_TREE);
        if (!tail) {
            out[(size_t)chunk * (BPB * N_OUTPUT) + tid] = s;   // coalesced, exactly once
        } else if (bg < N_BATCH) {
            atomicAdd(out + (size_t)bg * N_OUTPUT + o, s);
        }
    }
}

extern "C" void kernel_launch(void* const* d_in, const int* in_sizes, int n_in,
                              void* d_out, int out_size, void* d_ws, size_t ws_size,
                              hipStream_t stream) {
    const float* x         = (const float*)d_in[0];
    const int*   feature   = (const int*)d_in[1];
    const float* threshold = (const float*)d_in[2];
    const float* value     = (const float*)d_in[5];   // children implied by complete heap layout
    float* out = (float*)d_out;

    // zero only the tail-chunk region (atomic accumulation); ~27 KB
    const size_t tail_off = (size_t)FULL_CHUNKS * BPB * N_OUTPUT;
    if ((size_t)out_size > tail_off) {
        hipMemsetAsync(out + tail_off, 0, ((size_t)out_size - tail_off) * sizeof(float), stream);
    }

    tree_kernel<<<dim3(GRID), dim3(BLOCK), 0, stream>>>(x, feature, threshold, value, out);
}